// Round 8
// baseline (269.223 us; speedup 1.0000x reference)
//
#include <hip/hip_runtime.h>
#include <math.h>

#define NB 8
#define NN 2048
#define IN_DIM 256
#define OUT_DIM 64
#define ALPHA 0.2f
#define JSPLIT 4
#define PACK_BLOCKS (NB * NN * NN / 32 / 256)   // 16384: 32 ints/thread
#define WH_BLOCKS 256

typedef __attribute__((ext_vector_type(8))) short bf16x8;
typedef __attribute__((ext_vector_type(4))) float f32x4;
typedef __attribute__((ext_vector_type(4))) int   i32x4;

// float -> bf16 (RNE), bit trick (no NaN inputs here)
__device__ __forceinline__ unsigned short f2bf(float x) {
    union { float f; unsigned u; } v; v.f = x;
    unsigned r = v.u + 0x7FFF + ((v.u >> 16) & 1);
    return (unsigned short)(r >> 16);
}

// ---------------------------------------------------------------------------
// Kernel 1 (fused "prep"): blocks [0,256) = wh (Wh=h@W via MFMA -> Whbt
// [b][d][j] bf16, s1, s2 — same as R7); blocks [256, 256+16384) = adj bit-pack
// (32 ints -> 1 uint per thread; 128 MB -> 4 MB).  Pack is the HBM-stream
// shadow that hides wh's 1-wave/SIMD latency.
// ---------------------------------------------------------------------------
#define WT_STRIDE 264
__global__ __launch_bounds__(256) void prep_kernel(const float* __restrict__ h,
                                                   const float* __restrict__ W,
                                                   const float* __restrict__ a,
                                                   const int* __restrict__ adj,
                                                   unsigned* __restrict__ bits,
                                                   unsigned short* __restrict__ Whbt,
                                                   float* __restrict__ s1,
                                                   float* __restrict__ s2) {
    __shared__ unsigned short Wt[OUT_DIM * WT_STRIDE];
    const int t = threadIdx.x;
    const int bid = blockIdx.x;

    if (bid >= WH_BLOCKS) {
        // ---------------- pack role: 32 ints -> 1 uint ----------------
        const long w = (long)(bid - WH_BLOCKS) * 256 + t;   // uint index
        const i32x4* a4 = (const i32x4*)adj + w * 8;
        unsigned mm = 0;
        #pragma unroll
        for (int q = 0; q < 8; ++q) {
            const i32x4 v = __builtin_nontemporal_load(a4 + q);
            mm |= (v.x != 0 ? 1u : 0u) << (4 * q);
            mm |= (v.y != 0 ? 1u : 0u) << (4 * q + 1);
            mm |= (v.z != 0 ? 1u : 0u) << (4 * q + 2);
            mm |= (v.w != 0 ? 1u : 0u) << (4 * q + 3);
        }
        bits[w] = mm;
        return;
    }

    // ---------------- wh role (R7 structure) ----------------
    #pragma unroll 8
    for (int rep = 0; rep < 64; ++rep) {
        const int id = rep * 256 + t;
        const int k = id >> 6, n = id & 63;
        Wt[n * WT_STRIDE + k] = f2bf(W[id]);
    }
    __syncthreads();

    const int lane = t & 63, wv = t >> 6;
    const int m = lane & 15, quad = lane >> 4;
    const long gr0 = (long)(bid * 4 + wv) * 16;

    f32x4 acc[4];
    #pragma unroll
    for (int nt = 0; nt < 4; ++nt) acc[nt] = (f32x4){0.f, 0.f, 0.f, 0.f};

    #pragma unroll
    for (int ks = 0; ks < 8; ++ks) {
        const int k0 = ks * 32;
        const float* hp = h + (gr0 + m) * IN_DIM + k0 + quad * 8;
        const float4 ha = *(const float4*)hp;
        const float4 hb = *(const float4*)(hp + 4);
        bf16x8 af;
        af[0] = (short)f2bf(ha.x); af[1] = (short)f2bf(ha.y);
        af[2] = (short)f2bf(ha.z); af[3] = (short)f2bf(ha.w);
        af[4] = (short)f2bf(hb.x); af[5] = (short)f2bf(hb.y);
        af[6] = (short)f2bf(hb.z); af[7] = (short)f2bf(hb.w);
        #pragma unroll
        for (int nt = 0; nt < 4; ++nt) {
            const bf16x8 bf_ = *(const bf16x8*)(const void*)
                &Wt[(nt * 16 + m) * WT_STRIDE + k0 + quad * 8];
            acc[nt] = __builtin_amdgcn_mfma_f32_16x16x32_bf16(af, bf_, acc[nt], 0, 0, 0);
        }
    }

    const int b  = (int)(gr0 >> 11);
    const int ib = (int)(gr0 & 2047);

    #pragma unroll
    for (int nt = 0; nt < 4; ++nt) {
        ushort4 w4;
        w4.x = f2bf(acc[nt][0]); w4.y = f2bf(acc[nt][1]);
        w4.z = f2bf(acc[nt][2]); w4.w = f2bf(acc[nt][3]);
        *(ushort4*)&Whbt[((long)(b * OUT_DIM + nt * 16 + m) << 11) + ib + quad * 4] = w4;
    }

    float a1v[4], a2v[4];
    #pragma unroll
    for (int nt = 0; nt < 4; ++nt) {
        a1v[nt] = a[nt * 16 + m];
        a2v[nt] = a[OUT_DIM + nt * 16 + m];
    }
    #pragma unroll
    for (int reg = 0; reg < 4; ++reg) {
        float p1 = 0.f, p2 = 0.f;
        #pragma unroll
        for (int nt = 0; nt < 4; ++nt) {
            p1 += acc[nt][reg] * a1v[nt];
            p2 += acc[nt][reg] * a2v[nt];
        }
        #pragma unroll
        for (int off = 1; off < 16; off <<= 1) {
            p1 += __shfl_xor(p1, off, 64);
            p2 += __shfl_xor(p2, off, 64);
        }
        if (m == 0) {
            s1[gr0 + quad * 4 + reg] = p1;
            s2[gr0 + quad * 4 + reg] = p2;
        }
    }
}

// ---------------------------------------------------------------------------
// Kernel 2: masked softmax + P@Wh via bf16 MFMA, zero LDS/barriers, and now
// zero HBM streaming: mask bits (4 MB) + Whbt (2 MB) + s2 (64 KB) are
// L2/LLC-resident.  Each wave preloads its ENTIRE j-slice mask (16 dwords =
// 4 x i32x4) in the prologue; fully-unrolled 16 steps of 32 j.
// Denominators via 5th MFMA with B=1.0 (same rounded A-frag as numerator).
// ---------------------------------------------------------------------------
__device__ __forceinline__ float pcalc(unsigned mask, int bit, float s2e, float s1v) {
    float e = s1v + s2e;
    e = e > 0.f ? e : ALPHA * e;
    const float p = __expf(e);
    return ((mask >> bit) & 1u) ? p : 0.f;
}

__global__ __launch_bounds__(256, 4) void attn_kernel(const unsigned* __restrict__ bits,
                                                      const unsigned short* __restrict__ Whbt,
                                                      const float* __restrict__ s1,
                                                      const float* __restrict__ s2,
                                                      float* __restrict__ part,
                                                      float* __restrict__ lpart) {
    const int t = threadIdx.x, lane = t & 63, wv = t >> 6;
    const int bid = blockIdx.x;
    const int js  = bid & (JSPLIT - 1);
    const int itg = (bid >> 2) & 31;
    const int b   = bid >> 7;
    const int i0  = itg * 64 + wv * 16;
    const int jlo = js * (NN / JSPLIT);        // 512-wide j slice, 16 steps

    const int m = lane & 15, quad = lane >> 4;

    // whole-slice mask preload: row i0+m, dwords [jlo/32, jlo/32+16)
    const i32x4* mp = (const i32x4*)(bits + ((long)(b * NN + i0 + m) << 6) + (jlo >> 5));
    i32x4 mk[4];
    #pragma unroll
    for (int g = 0; g < 4; ++g) mk[g] = mp[g];

    const float* s2p  = s2 + b * NN + jlo + quad * 8;
    const unsigned short* wbase = Whbt + ((long)(b * OUT_DIM) << 11) + jlo + quad * 8;
    const float s1v = s1[b * NN + i0 + m];

    f32x4 acc[4];
    #pragma unroll
    for (int nt = 0; nt < 4; ++nt) acc[nt] = (f32x4){0.f, 0.f, 0.f, 0.f};
    f32x4 racc = (f32x4){0.f, 0.f, 0.f, 0.f};

    bf16x8 bones;
    #pragma unroll
    for (int e = 0; e < 8; ++e) bones[e] = (short)0x3F80;   // 1.0 bf16

    // s2 rotation, 1 step lookahead (L2-hot)
    float4 sv0 = *(const float4*)s2p;
    float4 sv1 = *(const float4*)(s2p + 4);

    #pragma unroll
    for (int ks = 0; ks < 16; ++ks) {          // FULL unroll: mk[] extracts fold
        const int j0 = ks * 32;
        const unsigned mask = (unsigned)mk[ks >> 2][ks & 3];

        bf16x8 bfr[4];
        #pragma unroll
        for (int nt = 0; nt < 4; ++nt)
            bfr[nt] = *(const bf16x8*)(const void*)
                &wbase[(((long)(nt * 16 + m)) << 11) + j0];

        const float4 cs0 = sv0, cs1 = sv1;
        if (ks < 15) {
            sv0 = *(const float4*)(s2p + j0 + 32);
            sv1 = *(const float4*)(s2p + j0 + 36);
        }

        const int bb = quad * 8;
        float pv[8];
        pv[0] = pcalc(mask, bb + 0, cs0.x, s1v);
        pv[1] = pcalc(mask, bb + 1, cs0.y, s1v);
        pv[2] = pcalc(mask, bb + 2, cs0.z, s1v);
        pv[3] = pcalc(mask, bb + 3, cs0.w, s1v);
        pv[4] = pcalc(mask, bb + 4, cs1.x, s1v);
        pv[5] = pcalc(mask, bb + 5, cs1.y, s1v);
        pv[6] = pcalc(mask, bb + 6, cs1.z, s1v);
        pv[7] = pcalc(mask, bb + 7, cs1.w, s1v);

        bf16x8 af;
        #pragma unroll
        for (int e = 0; e < 8; ++e) af[e] = (short)f2bf(pv[e]);

        #pragma unroll
        for (int nt = 0; nt < 4; ++nt)
            acc[nt] = __builtin_amdgcn_mfma_f32_16x16x32_bf16(af, bfr[nt], acc[nt], 0, 0, 0);
        racc = __builtin_amdgcn_mfma_f32_16x16x32_bf16(af, bones, racc, 0, 0, 0);
    }

    // ---- l partial: racc[reg] = rowsum(i0+quad*4+reg), replicated over m ----
    if (m == 0) {
        #pragma unroll
        for (int reg = 0; reg < 4; ++reg)
            lpart[js * (NB * NN) + b * NN + i0 + quad * 4 + reg] = racc[reg];
    }

    // ---- out partials.  C layout: i = i0+quad*4+reg, d = nt*16+m ----
    float* pp = part + (long)js * ((long)NB * NN * OUT_DIM)
                     + ((long)(b * NN + i0) << 6);
    #pragma unroll
    for (int nt = 0; nt < 4; ++nt)
        #pragma unroll
        for (int reg = 0; reg < 4; ++reg)
            pp[(quad * 4 + reg) * OUT_DIM + nt * 16 + m] = acc[nt][reg];
}

// ---------------------------------------------------------------------------
// Kernel 3: out = (sum_js part) / (sum_js lpart), float4 coalesced.
// ---------------------------------------------------------------------------
__global__ __launch_bounds__(256) void finalize_kernel(const float* __restrict__ part,
                                                       const float* __restrict__ lpart,
                                                       float* __restrict__ out) {
    const int idx = blockIdx.x * 256 + threadIdx.x;
    const int row = idx >> 4;
    float l = 0.f;
    #pragma unroll
    for (int s = 0; s < JSPLIT; ++s) l += lpart[s * (NB * NN) + row];
    float4 v = make_float4(0.f, 0.f, 0.f, 0.f);
    const float4* p4 = (const float4*)part;
    #pragma unroll
    for (int s = 0; s < JSPLIT; ++s) {
        const float4 p = p4[(long)s * ((long)NB * NN * OUT_DIM / 4) + idx];
        v.x += p.x; v.y += p.y; v.z += p.z; v.w += p.w;
    }
    const float inv = 1.f / l;
    v.x *= inv; v.y *= inv; v.z *= inv; v.w *= inv;
    ((float4*)out)[idx] = v;
}

// ---------------------------------------------------------------------------
extern "C" void kernel_launch(void* const* d_in, const int* in_sizes, int n_in,
                              void* d_out, int out_size, void* d_ws, size_t ws_size,
                              hipStream_t stream) {
    const float* h   = (const float*)d_in[0];
    const int*   adj = (const int*)d_in[1];
    const float* W   = (const float*)d_in[2];
    const float* a   = (const float*)d_in[3];
    float* out = (float*)d_out;

    float* s1    = (float*)d_ws;                          // 16K f32
    float* s2    = s1 + NB * NN;                          // 16K f32
    float* lpart = s2 + NB * NN;                          // 64K f32
    float* part  = lpart + JSPLIT * NB * NN;              // 4M f32 = 16 MB
    unsigned short* Whbt =
        (unsigned short*)(part + (long)JSPLIT * NB * NN * OUT_DIM);  // 1M bf16 = 2 MB
    unsigned* bits = (unsigned*)(Whbt + (long)NB * NN * OUT_DIM);    // 1M uint = 4 MB

    prep_kernel<<<WH_BLOCKS + PACK_BLOCKS, 256, 0, stream>>>(h, W, a, adj, bits,
                                                             Whbt, s1, s2);
    attn_kernel<<<NB * (NN / 64) * JSPLIT, 256, 0, stream>>>(bits, Whbt, s1, s2,
                                                             part, lpart);
    finalize_kernel<<<NB * NN * OUT_DIM / 4 / 256, 256, 0, stream>>>(part, lpart, out);
}